// Round 6
// baseline (630.252 us; speedup 1.0000x reference)
//
#include <hip/hip_runtime.h>

#define QLEN 512
#define MLEN 512
#define KLEN 1024
#define BB   8
#define DMODEL 1024
#define NH   16
#define HD   64
#define NF   384
#define ATT_SCALE 0.125f
#define EPSV 1e-5f

typedef float v4f __attribute__((ext_vector_type(4)));
typedef short bf16x8 __attribute__((ext_vector_type(8)));
typedef unsigned int u32x4 __attribute__((ext_vector_type(4)));
typedef unsigned short u16x8 __attribute__((ext_vector_type(8)));

__device__ __forceinline__ unsigned short f2bf(float f) {
    unsigned int x = __builtin_bit_cast(unsigned int, f);
    x += 0x7fffu + ((x >> 16) & 1u);
    return (unsigned short)(x >> 16);
}

__device__ __forceinline__ void gll16(const void* g, void* l) {
    __builtin_amdgcn_global_load_lds(
        (const __attribute__((address_space(1))) unsigned int*)g,
        (__attribute__((address_space(3))) unsigned int*)l, 16, 0, 0);
}

// feature layouts (elements):
//   qf2[hh][rb(8)][c(48)][b(8)][row(64)][e(8)]   stride per (hh,rb) = 196608
//   kf2[hh][rb(16)][c(48)][b(8)][row(64)][e(8)]  stride per (hh,rb) = 196608
#define FCB 4096      // els per chunk-block: 8b*64row*8e
#define FRB 196608    // els per (hh,rb): 48*FCB

// ---------------------------------------------------------------------------
// Fused f32->bf16 converts: mems+h -> cbf (c matrix), weights -> bf16 scratch
// ---------------------------------------------------------------------------
__global__ __launch_bounds__(256)
void cvt_all_kernel(const float* __restrict__ h, const float* __restrict__ mems,
                    const float* __restrict__ Wq, const float* __restrict__ Wkv,
                    const float* __restrict__ Wo,
                    unsigned short* __restrict__ cbf, unsigned short* __restrict__ wqb,
                    unsigned short* __restrict__ wkvb, unsigned short* __restrict__ wob)
{
    int blk = blockIdx.x;
    const float* src; unsigned short* dst; int base;
    if (blk < 4096)       { src = mems; dst = cbf;           base = blk; }
    else if (blk < 8192)  { src = h;    dst = cbf + 4194304; base = blk - 4096; }
    else if (blk < 9216)  { src = Wq;   dst = wqb;           base = blk - 8192; }
    else if (blk < 11264) { src = Wkv;  dst = wkvb;          base = blk - 9216; }
    else                  { src = Wo;   dst = wob;           base = blk - 11264; }
    int i = (base * 256 + threadIdx.x) * 4;
    v4f v = *(const v4f*)(src + i);
    unsigned int p0, p1;
    asm("v_cvt_pk_bf16_f32 %0, %1, %2" : "=v"(p0) : "v"(v[0]), "v"(v[1]));
    asm("v_cvt_pk_bf16_f32 %0, %1, %2" : "=v"(p1) : "v"(v[2]), "v"(v[3]));
    uint2 u; u.x = p0; u.y = p1;
    *(uint2*)(dst + i) = u;
}

// ---------------------------------------------------------------------------
// MFMA GEMM 128x128 (BK=64, 4 waves x 64x64) with fused DPFP-feature epilogue.
// MODE 0: q-proj -> qf2 features           (feat = qf2)
// MODE 1: kv-proj; n0<1024 -> kf2 features; n0>=1024 -> vraw bf16 rows
// MODE 2: o-proj -> xo f32 = C + hres
// Epilogue (0/1-K): acc -> Cs bf16 (overlays As/Bs), thread = (row, head-half)
// computes 384 DPFP features, stores chunk-blocked coalesced.
// ---------------------------------------------------------------------------
#define GEXT(a) ((a) < 64 ? ((a) & 1 ? __builtin_bit_cast(float, glo[(a) >> 1] & 0xffff0000u) \
                                     : __builtin_bit_cast(float, glo[(a) >> 1] << 16)) \
                          : ((a) & 1 ? __builtin_bit_cast(float, ghi[((a) - 64) >> 1] & 0xffff0000u) \
                                     : __builtin_bit_cast(float, ghi[((a) - 64) >> 1] << 16)))

template<int MODE>
__global__ __launch_bounds__(256)
void mm128_kernel(const unsigned short* __restrict__ Abf,
                  const unsigned short* __restrict__ Bbf,
                  const float* __restrict__ hres,
                  unsigned short* __restrict__ feat,
                  unsigned short* __restrict__ vout,
                  float* __restrict__ xo)
{
    __shared__ __align__(16) char smem[128 * 136 * 2];   // 34816 B
    unsigned short* As = (unsigned short*)smem;            // 16 KB
    unsigned short* Bs = (unsigned short*)(smem + 16384);  // 16 KB
    unsigned short* Cs = (unsigned short*)smem;            // overlay [128][136]

    const int t  = threadIdx.x;
    const int w  = t >> 6;
    const int l  = t & 63;
    const int lj = l & 15;
    const int lg = l >> 4;
    const int m0 = blockIdx.x * 128;
    const int n0 = blockIdx.y * 128;
    const int wr = w >> 1, wc = w & 1;
    const int rsub = l >> 3;
    const int csw  = ((l & 7) ^ rsub) * 16;

    v4f acc[4][4] = {};

    for (int s = 0; s < 16; ++s) {
        const int k0b = s * 128;
        __syncthreads();
        #pragma unroll
        for (int u = 0; u < 4; ++u) {
            int ra = w * 32 + u * 8;
            gll16((const char*)Abf + (size_t)(m0 + ra + rsub) * 2048 + k0b + csw,
                  (char*)As + ra * 128);
            gll16((const char*)Bbf + (size_t)(n0 + ra + rsub) * 2048 + k0b + csw,
                  (char*)Bs + ra * 128);
        }
        __syncthreads();
        #pragma unroll
        for (int ks = 0; ks < 2; ++ks) {
            bf16x8 af[4], bfr[4];
            #pragma unroll
            for (int m = 0; m < 4; ++m) {
                int row = wr * 64 + m * 16 + lj;
                int c = ks * 4 + lg;
                af[m] = *(const bf16x8*)((const char*)As + row * 128 +
                                         ((c ^ (row & 7)) * 16));
            }
            #pragma unroll
            for (int nn = 0; nn < 4; ++nn) {
                int row = wc * 64 + nn * 16 + lj;
                int c = ks * 4 + lg;
                bfr[nn] = *(const bf16x8*)((const char*)Bs + row * 128 +
                                           ((c ^ (row & 7)) * 16));
            }
            #pragma unroll
            for (int m = 0; m < 4; ++m)
                #pragma unroll
                for (int nn = 0; nn < 4; ++nn)
                    acc[m][nn] = __builtin_amdgcn_mfma_f32_16x16x32_bf16(
                                     af[m], bfr[nn], acc[m][nn], 0, 0, 0);
        }
    }

    if constexpr (MODE == 2) {
        #pragma unroll
        for (int m = 0; m < 4; ++m) {
            #pragma unroll
            for (int rr = 0; rr < 4; ++rr) {
                int row = m0 + wr * 64 + m * 16 + 4 * lg + rr;
                #pragma unroll
                for (int nn = 0; nn < 4; ++nn) {
                    int col = n0 + wc * 64 + nn * 16 + lj;
                    xo[(size_t)row * 1024 + col] =
                        acc[m][nn][rr] + hres[(size_t)row * 1024 + col];
                }
            }
        }
        return;
    }

    if (MODE == 1 && n0 >= 1024) {
        // V half: plain bf16 row stores (vtrans handles the transpose)
        #pragma unroll
        for (int m = 0; m < 4; ++m) {
            #pragma unroll
            for (int rr = 0; rr < 4; ++rr) {
                int row = m0 + wr * 64 + m * 16 + 4 * lg + rr;
                #pragma unroll
                for (int nn = 0; nn < 4; ++nn) {
                    int col = n0 - 1024 + wc * 64 + nn * 16 + lj;
                    vout[(size_t)row * 1024 + col] = f2bf(acc[m][nn][rr]);
                }
            }
        }
        return;
    }

    // ---- K/Q feature epilogue ----
    __syncthreads();   // all As/Bs reads done; safe to overlay Cs
    #pragma unroll
    for (int m = 0; m < 4; ++m)
        #pragma unroll
        for (int rr = 0; rr < 4; ++rr) {
            int row = wr * 64 + m * 16 + 4 * lg + rr;
            #pragma unroll
            for (int nn = 0; nn < 4; ++nn)
                Cs[row * 136 + wc * 64 + nn * 16 + lj] = f2bf(acc[m][nn][rr]);
        }
    __syncthreads();

    const int fr = t & 127;          // tile row
    const int hs = t >> 7;           // head half of the 128 cols
    unsigned int xr[32];
    #pragma unroll
    for (int c8 = 0; c8 < 8; ++c8) {
        u32x4 v = *(const u32x4*)&Cs[fr * 136 + hs * 64 + c8 * 8];
        xr[c8 * 4 + 0] = v[0]; xr[c8 * 4 + 1] = v[1];
        xr[c8 * 4 + 2] = v[2]; xr[c8 * 4 + 3] = v[3];
    }

    unsigned int glo[32], ghi[32];
    #pragma unroll
    for (int p = 0; p < 32; ++p) {
        float x0 = __builtin_bit_cast(float, xr[p] << 16);
        float x1 = __builtin_bit_cast(float, xr[p] & 0xffff0000u);
        float a0 = fmaxf(x0, 0.f), a1 = fmaxf(x1, 0.f);
        float b0 = fmaxf(-x0, 0.f), b1 = fmaxf(-x1, 0.f);
        asm("v_cvt_pk_bf16_f32 %0, %1, %2" : "=v"(glo[p]) : "v"(a0), "v"(a1));
        asm("v_cvt_pk_bf16_f32 %0, %1, %2" : "=v"(ghi[p]) : "v"(b0), "v"(b1));
    }

    const int grow = m0 + fr;
    const int seq  = grow >> 3;
    const int b    = grow & 7;
    const int hh   = (n0 >> 6) + hs;
    const int rb   = seq >> 6;
    const int rloc = seq & 63;
    const int nrb  = (MODE == 0) ? 8 : 16;
    unsigned short* dst = feat + (size_t)(hh * nrb + rb) * FRB + b * 512 + rloc * 8;

    #pragma unroll
    for (int f0 = 0; f0 < NF; f0 += 8) {
        unsigned int w4[4];
        #pragma unroll
        for (int q2 = 0; q2 < 4; ++q2) {
            const int f  = f0 + q2 * 2;
            const int r0 = (f >> 7) + 1,       t0 = f & 127,       u0 = (t0 - r0) & 127;
            const int r1 = ((f + 1) >> 7) + 1, t1 = (f + 1) & 127, u1 = (t1 - r1) & 127;
            float p0 = GEXT(t0) * GEXT(u0);
            float p1 = GEXT(t1) * GEXT(u1);
            asm("v_cvt_pk_bf16_f32 %0, %1, %2" : "=v"(w4[q2]) : "v"(p0), "v"(p1));
        }
        u32x4 st = {w4[0], w4[1], w4[2], w4[3]};
        *(u32x4*)(dst + (f0 >> 3) * FCB) = st;
    }
}

// ---------------------------------------------------------------------------
// V transpose: v_raw [8192=(j,b)][1024=(h,d)] bf16 -> vt [b,h][d][KLEN] bf16.
// ---------------------------------------------------------------------------
__global__ __launch_bounds__(256)
void vtrans_kernel(const unsigned short* __restrict__ vraw,
                   unsigned short* __restrict__ vt)
{
    __shared__ unsigned short S[256][72];
    const int t  = threadIdx.x;
    const int jc = blockIdx.x, hh = blockIdx.y, b = blockIdx.z;
    const unsigned short* src = vraw + (size_t)((jc * 256 + t) * 8 + b) * 1024 + hh * 64;
    #pragma unroll
    for (int c = 0; c < 8; ++c)
        *(u32x4*)&S[t][c * 8] = *(const u32x4*)(src + c * 8);
    __syncthreads();
    const int d = t >> 2, qq = t & 3;
    unsigned short* dst = vt + ((size_t)(b * NH + hh) * HD + d) * KLEN + jc * 256 + qq * 64;
    #pragma unroll
    for (int c8 = 0; c8 < 8; ++c8) {
        u16x8 o;
        #pragma unroll
        for (int e = 0; e < 8; ++e) o[e] = S[qq * 64 + c8 * 8 + e][d];
        *(u16x8*)(dst + c8 * 8) = o;
    }
}

// ---------------------------------------------------------------------------
// MFMA attention, K/V LDS-staged per j-tile. Panel-grouped XCD swizzle:
// bid = P%8 + 8*it + 64*(P/8); P%8 = hh%8, so all b of one hh share an XCD.
// qf2/kf2 per layouts above.
// ---------------------------------------------------------------------------
__global__ __launch_bounds__(256)
void attn_mfma_kernel(const unsigned short* __restrict__ qf,
                      const unsigned short* __restrict__ kf,
                      const unsigned short* __restrict__ vt,
                      unsigned short* __restrict__ avec)
{
    __shared__ unsigned short Ks[64 * 384];   // rows 768B, chunk^row&7 swizzle
    __shared__ unsigned short Vs[64 * 64];
    __shared__ float Ss[64][68];

    const int t  = threadIdx.x;
    const int w  = t >> 6;
    const int l  = t & 63;
    const int lj = l & 15;
    const int lg = l >> 4;

    const int bid = blockIdx.x;
    const int P   = (bid & 7) + ((bid >> 6) << 3);  // panel 0..127
    const int it  = (bid >> 3) & 7;
    const int n   = P & 15;
    const int b   = P >> 4;

    const unsigned short* qpan = qf + (size_t)(n * 8 + it) * FRB + b * 512;
    const char* kpan = (const char*)kf + (size_t)(n * 16) * (FRB * 2);
    const unsigned short* vbase = vt + (size_t)(b * NH + n) * HD * KLEN;

    // K staging: LDS 16B-slot S16=(w*12+u)*64+l -> (row, c_lds); source chunk
    // cg = unXOR(c_lds); source byte (within jt block) = (cg*8+b)*1024 + row*16
    int koff[12];
    #pragma unroll
    for (int u = 0; u < 12; ++u) {
        int S16 = (w * 12 + u) * 64 + l;
        int row = S16 / 48;
        int c   = S16 - row * 48;
        int cg  = (c & ~7) | ((c & 7) ^ (row & 7));
        koff[u] = (cg * 8 + b) * 1024 + row * 16;
    }
    int voff[2];
    #pragma unroll
    for (int uu = 0; uu < 2; ++uu) {
        int d = (w * 2 + uu) * 8 + (l >> 3);
        int c = (l & 7) ^ (l >> 3);
        voff[uu] = d * (KLEN * 2) + c * 16;
    }

    // Q fragments: 16 lanes read 256B contiguous per frag
    bf16x8 qfr[12];
    #pragma unroll
    for (int ks = 0; ks < 12; ++ks)
        qfr[ks] = *(const bf16x8*)(qpan + (size_t)(ks * 4 + lg) * FCB + (w * 16 + lj) * 8);

    v4f num[4] = {};
    float den[4] = {0.f, 0.f, 0.f, 0.f};

    const int jt_end = it + 8;
    for (int jt = 0; jt <= jt_end; ++jt) {
        __syncthreads();
        const char* ktile = kpan + (size_t)jt * 393216;
        #pragma unroll
        for (int u = 0; u < 12; ++u)
            gll16(ktile + koff[u], (char*)Ks + (w * 12 + u) * 1024);
        const char* vtile = (const char*)vbase + jt * 128;
        #pragma unroll
        for (int uu = 0; uu < 2; ++uu)
            gll16(vtile + voff[uu], (char*)Vs + (w * 2 + uu) * 1024);
        __syncthreads();

        v4f sacc[4] = {};
        #pragma unroll
        for (int jf = 0; jf < 4; ++jf) {
            const int row = jf * 16 + lj;
            const char* krow = (const char*)Ks + row * 768;
            #pragma unroll
            for (int ks = 0; ks < 12; ++ks) {
                int c   = ks * 4 + lg;
                int swz = (c & ~7) | ((c & 7) ^ (row & 7));
                bf16x8 kfr = *(const bf16x8*)(krow + swz * 16);
                sacc[jf] = __builtin_amdgcn_mfma_f32_16x16x32_bf16(
                               qfr[ks], kfr, sacc[jf], 0, 0, 0);
            }
        }

        const bool diag = (jt == jt_end);
        #pragma unroll
        for (int jf = 0; jf < 4; ++jf) {
            #pragma unroll
            for (int r = 0; r < 4; ++r) {
                float sv = sacc[jf][r];
                int li  = 4 * lg + r;
                int ljj = jf * 16 + lj;
                if (diag && ljj > (w * 16 + li)) sv = 0.f;
                den[r] += sv;
                Ss[w * 16 + li][ljj] = sv;
            }
        }

        #pragma unroll
        for (int kk = 0; kk < 2; ++kk) {
            const float* prow = &Ss[w * 16 + lj][kk * 32 + lg * 8];
            v4f plo = *(const v4f*)prow;
            v4f phi = *(const v4f*)(prow + 4);
            unsigned int w0, w1, w2, w3;
            asm("v_cvt_pk_bf16_f32 %0, %1, %2" : "=v"(w0) : "v"(plo[0]), "v"(plo[1]));
            asm("v_cvt_pk_bf16_f32 %0, %1, %2" : "=v"(w1) : "v"(plo[2]), "v"(plo[3]));
            asm("v_cvt_pk_bf16_f32 %0, %1, %2" : "=v"(w2) : "v"(phi[0]), "v"(phi[1]));
            asm("v_cvt_pk_bf16_f32 %0, %1, %2" : "=v"(w3) : "v"(phi[2]), "v"(phi[3]));
            u32x4 pw = {w0, w1, w2, w3};
            bf16x8 pa = __builtin_bit_cast(bf16x8, pw);
            #pragma unroll
            for (int fd = 0; fd < 4; ++fd) {
                int row = fd * 16 + lj;
                int swz = (kk * 4 + lg) ^ (row & 7);
                bf16x8 vb = *(const bf16x8*)((const char*)Vs + row * 128 + swz * 16);
                num[fd] = __builtin_amdgcn_mfma_f32_16x16x32_bf16(
                              pa, vb, num[fd], 0, 0, 0);
            }
        }
    }

    #pragma unroll
    for (int r = 0; r < 4; ++r) {
        float v = den[r];
        v += __shfl_xor(v, 1, 16);
        v += __shfl_xor(v, 2, 16);
        v += __shfl_xor(v, 4, 16);
        v += __shfl_xor(v, 8, 16);
        den[r] = v;
    }

    #pragma unroll
    for (int r = 0; r < 4; ++r) {
        float minv = ATT_SCALE / (den[r] * ATT_SCALE + EPSV);
        int gi = it * 64 + w * 16 + 4 * lg + r;
        unsigned short* orow = avec + ((size_t)gi * BB + b) * DMODEL + n * HD;
        #pragma unroll
        for (int fd = 0; fd < 4; ++fd)
            orow[fd * 16 + lj] = f2bf(num[fd][r] * minv);
    }
}

// ---------------------------------------------------------------------------
// Row LayerNorm over DM=1024.
// ---------------------------------------------------------------------------
__global__ __launch_bounds__(256)
void ln_kernel(const float* __restrict__ x, const float* __restrict__ gamma,
               const float* __restrict__ beta, float* __restrict__ out)
{
    const int row = blockIdx.x;
    const int t = threadIdx.x;
    const float* xr = x + (size_t)row * DMODEL;
    v4f xv = *(const v4f*)(xr + (t << 2));
    float s1 = xv[0] + xv[1] + xv[2] + xv[3];
    float s2 = xv[0]*xv[0] + xv[1]*xv[1] + xv[2]*xv[2] + xv[3]*xv[3];
    #pragma unroll
    for (int off = 32; off > 0; off >>= 1) {
        s1 += __shfl_down(s1, off);
        s2 += __shfl_down(s2, off);
    }
    __shared__ float red[2][4];
    __shared__ float mv[2];
    const int wave = t >> 6;
    if ((t & 63) == 0) { red[0][wave] = s1; red[1][wave] = s2; }
    __syncthreads();
    if (t == 0) {
        float a = red[0][0] + red[0][1] + red[0][2] + red[0][3];
        float q = red[1][0] + red[1][1] + red[1][2] + red[1][3];
        float mu  = a * (1.f / DMODEL);
        float var = q * (1.f / DMODEL) - mu * mu;
        mv[0] = mu;
        mv[1] = rsqrtf(var + EPSV);
    }
    __syncthreads();
    float mu = mv[0], rs = mv[1];
    v4f gv = *(const v4f*)(gamma + (t << 2));
    v4f bv = *(const v4f*)(beta + (t << 2));
    v4f o;
    #pragma unroll
    for (int e = 0; e < 4; ++e) o[e] = (xv[e] - mu) * rs * gv[e] + bv[e];
    *(v4f*)(out + (size_t)row * DMODEL + (t << 2)) = o;
}

extern "C" void kernel_launch(void* const* d_in, const int* in_sizes, int n_in,
                              void* d_out, int out_size, void* d_ws, size_t ws_size,
                              hipStream_t stream)
{
    const float* h     = (const float*)d_in[0];
    const float* mems  = (const float*)d_in[1];
    const float* Wq    = (const float*)d_in[2];
    const float* Wkv   = (const float*)d_in[3];
    const float* Wo    = (const float*)d_in[4];
    const float* gamma = (const float*)d_in[5];
    const float* beta  = (const float*)d_in[6];
    // d_in[7] = attn_mask: causal structure computed analytically, ignored.

    char* ws = (char*)d_ws;
    unsigned short* qf   = (unsigned short*)(ws);             // 50.33 MB
    unsigned short* kf   = (unsigned short*)(ws + 50331648);  // 100.66 MB
    unsigned short* vraw = (unsigned short*)(ws + 150994944); // 16.78 MB
    unsigned short* vt   = (unsigned short*)(ws + 167772160); // 16.78 MB
    unsigned short* cbf  = (unsigned short*)(ws + 184549376); // 16.78 MB
    unsigned short* avec = cbf;                               // overlay after projections
    float* xws = (float*)(ws);                                // overlay qf after attn

    unsigned short* wqb  = (unsigned short*)d_out;            // bf16 weights in d_out
    unsigned short* wkvb = wqb + 1048576;
    unsigned short* wob  = wkvb + 2097152;

    cvt_all_kernel<<<12288, 256, 0, stream>>>(h, mems, Wq, Wkv, Wo, cbf, wqb, wkvb, wob);
    mm128_kernel<1><<<dim3(64, 16), 256, 0, stream>>>(cbf, wkvb, nullptr, kf, vraw, nullptr);
    mm128_kernel<0><<<dim3(32, 8), 256, 0, stream>>>(cbf + 4194304, wqb, nullptr, qf, nullptr, nullptr);
    vtrans_kernel<<<dim3(4, 16, 8), 256, 0, stream>>>(vraw, vt);
    attn_mfma_kernel<<<1024, 256, 0, stream>>>(qf, kf, vt, avec);
    mm128_kernel<2><<<dim3(32, 8), 256, 0, stream>>>(avec, wob, h, nullptr, nullptr, xws);
    ln_kernel<<<4096, 256, 0, stream>>>(xws, gamma, beta, (float*)d_out);
}

// Round 7
// 264.885 us; speedup vs baseline: 2.3793x; 2.3793x over previous
//
#include <hip/hip_runtime.h>

#define QLEN 512
#define MLEN 512
#define KLEN 1024
#define BB   8
#define DMODEL 1024
#define NH   16
#define HD   64
#define NF   384
#define ATT_SCALE 0.125f
#define EPSV 1e-5f

typedef float v4f __attribute__((ext_vector_type(4)));
typedef short bf16x8 __attribute__((ext_vector_type(8)));
typedef unsigned int u32x4 __attribute__((ext_vector_type(4)));
typedef unsigned short u16x8 __attribute__((ext_vector_type(8)));

__device__ __forceinline__ unsigned short f2bf(float f) {
    unsigned int x = __builtin_bit_cast(unsigned int, f);
    x += 0x7fffu + ((x >> 16) & 1u);
    return (unsigned short)(x >> 16);
}

__device__ __forceinline__ void gll16(const void* g, void* l) {
    __builtin_amdgcn_global_load_lds(
        (const __attribute__((address_space(1))) unsigned int*)g,
        (__attribute__((address_space(3))) unsigned int*)l, 16, 0, 0);
}

// ---------------------------------------------------------------------------
// Fused f32->bf16 converts: mems+h -> cbf (c matrix), weights -> bf16 scratch
// ---------------------------------------------------------------------------
__global__ __launch_bounds__(256)
void cvt_all_kernel(const float* __restrict__ h, const float* __restrict__ mems,
                    const float* __restrict__ Wq, const float* __restrict__ Wkv,
                    const float* __restrict__ Wo,
                    unsigned short* __restrict__ cbf, unsigned short* __restrict__ wqb,
                    unsigned short* __restrict__ wkvb, unsigned short* __restrict__ wob)
{
    int blk = blockIdx.x;
    const float* src; unsigned short* dst; int base;
    if (blk < 4096)       { src = mems; dst = cbf;           base = blk; }
    else if (blk < 8192)  { src = h;    dst = cbf + 4194304; base = blk - 4096; }
    else if (blk < 9216)  { src = Wq;   dst = wqb;           base = blk - 8192; }
    else if (blk < 11264) { src = Wkv;  dst = wkvb;          base = blk - 9216; }
    else                  { src = Wo;   dst = wob;           base = blk - 11264; }
    int i = (base * 256 + threadIdx.x) * 4;
    v4f v = *(const v4f*)(src + i);
    unsigned int p0, p1;
    asm("v_cvt_pk_bf16_f32 %0, %1, %2" : "=v"(p0) : "v"(v[0]), "v"(v[1]));
    asm("v_cvt_pk_bf16_f32 %0, %1, %2" : "=v"(p1) : "v"(v[2]), "v"(v[3]));
    uint2 u; u.x = p0; u.y = p1;
    *(uint2*)(dst + i) = u;
}

// ---------------------------------------------------------------------------
// Pure MFMA GEMM, 128x128 tile, BK=64, 4 waves (each 64x64 = 4x4 frags).
// MODE 0: out = q_raw bf16; MODE 1: outK/outV = k_raw/v_raw bf16;
// MODE 2: xo f32 = C + hres
// ---------------------------------------------------------------------------
template<int MODE>
__global__ __launch_bounds__(256)
void mm128_kernel(const unsigned short* __restrict__ Abf,
                  const unsigned short* __restrict__ Bbf,
                  const float* __restrict__ hres,
                  unsigned short* __restrict__ outK,
                  unsigned short* __restrict__ outV,
                  float* __restrict__ xo)
{
    __shared__ unsigned short As[128 * 64];
    __shared__ unsigned short Bs[128 * 64];

    const int t  = threadIdx.x;
    const int w  = t >> 6;
    const int l  = t & 63;
    const int lj = l & 15;
    const int lg = l >> 4;
    const int m0 = blockIdx.x * 128;
    const int n0 = blockIdx.y * 128;
    const int wr = w >> 1, wc = w & 1;
    const int rsub = l >> 3;
    const int csw  = ((l & 7) ^ rsub) * 16;

    v4f acc[4][4] = {};

    for (int s = 0; s < 16; ++s) {
        const int k0b = s * 128;
        __syncthreads();
        #pragma unroll
        for (int u = 0; u < 4; ++u) {
            int ra = w * 32 + u * 8;
            gll16((const char*)Abf + (size_t)(m0 + ra + rsub) * 2048 + k0b + csw,
                  (char*)As + ra * 128);
            gll16((const char*)Bbf + (size_t)(n0 + ra + rsub) * 2048 + k0b + csw,
                  (char*)Bs + ra * 128);
        }
        __syncthreads();
        #pragma unroll
        for (int ks = 0; ks < 2; ++ks) {
            bf16x8 af[4], bfr[4];
            #pragma unroll
            for (int m = 0; m < 4; ++m) {
                int row = wr * 64 + m * 16 + lj;
                int c = ks * 4 + lg;
                af[m] = *(const bf16x8*)((const char*)As + row * 128 +
                                         ((c ^ (row & 7)) * 16));
            }
            #pragma unroll
            for (int nn = 0; nn < 4; ++nn) {
                int row = wc * 64 + nn * 16 + lj;
                int c = ks * 4 + lg;
                bfr[nn] = *(const bf16x8*)((const char*)Bs + row * 128 +
                                           ((c ^ (row & 7)) * 16));
            }
            #pragma unroll
            for (int m = 0; m < 4; ++m)
                #pragma unroll
                for (int nn = 0; nn < 4; ++nn)
                    acc[m][nn] = __builtin_amdgcn_mfma_f32_16x16x32_bf16(
                                     af[m], bfr[nn], acc[m][nn], 0, 0, 0);
        }
    }

    #pragma unroll
    for (int m = 0; m < 4; ++m) {
        #pragma unroll
        for (int rr = 0; rr < 4; ++rr) {
            int row = m0 + wr * 64 + m * 16 + 4 * lg + rr;
            #pragma unroll
            for (int nn = 0; nn < 4; ++nn) {
                int col = n0 + wc * 64 + nn * 16 + lj;
                float v = acc[m][nn][rr];
                if constexpr (MODE == 2) {
                    xo[(size_t)row * 1024 + col] = v + hres[(size_t)row * 1024 + col];
                } else if constexpr (MODE == 0) {
                    outK[(size_t)row * 1024 + col] = f2bf(v);
                } else {
                    if (n0 < 1024) outK[(size_t)row * 1024 + col] = f2bf(v);
                    else           outV[(size_t)row * 1024 + (col - 1024)] = f2bf(v);
                }
            }
        }
    }
}

// ---------------------------------------------------------------------------
// DPFP feature kernel v2 — LDS-resident g (no register arrays -> no scratch).
// Block = 128 rows x 1 head. Stage raw 16KB coalesced (full lines), relu'd
// into G[128][138] u16 (276B rows: 69-dword stride, conflict-free). Waves
// 0/2 compute features 0..191, waves 1/3 features 192..383 (wave-uniform ->
// both halves fully static: ds_read_u16 with immediate offsets).
// Output chunk-blocked: [bh][rb][c48][row64][e8]; stores 1KB contiguous.
// ---------------------------------------------------------------------------
__device__ __forceinline__ float gld(const unsigned short* gr, int idx) {
    return __builtin_bit_cast(float, ((unsigned int)gr[idx]) << 16);
}

template<int FBASE>
__device__ __forceinline__ void dpfp_half(const unsigned short* __restrict__ gr,
                                          unsigned short* __restrict__ drow)
{
    #pragma unroll
    for (int c = 0; c < 24; ++c) {
        unsigned int w4[4];
        #pragma unroll
        for (int q2 = 0; q2 < 4; ++q2) {
            const int f  = FBASE + c * 8 + q2 * 2;
            const int r0 = (f >> 7) + 1,       t0 = f & 127,       u0 = (t0 - r0) & 127;
            const int f1 = f + 1;
            const int r1 = (f1 >> 7) + 1,      t1 = f1 & 127,      u1 = (t1 - r1) & 127;
            float p0 = gld(gr, t0) * gld(gr, u0);
            float p1 = gld(gr, t1) * gld(gr, u1);
            asm("v_cvt_pk_bf16_f32 %0, %1, %2" : "=v"(w4[q2]) : "v"(p0), "v"(p1));
        }
        u32x4 st = {w4[0], w4[1], w4[2], w4[3]};
        *(u32x4*)(drow + c * 512) = st;
    }
}

__global__ __launch_bounds__(256)
void dpfp_kernel(const unsigned short* __restrict__ qraw,
                 const unsigned short* __restrict__ kraw,
                 unsigned short* __restrict__ qf, unsigned short* __restrict__ kf)
{
    __shared__ unsigned short G[128 * 138];   // 35328 B

    const int t   = threadIdx.x;
    const int blk = blockIdx.x;

    const unsigned short* src; unsigned short* dst; int b, hh, seq0;
    if (blk < 512) {                 // q: bh(128) x 4 groups of 128 i
        int bh = blk >> 2, ig = blk & 3;
        b = bh >> 4; hh = bh & 15; seq0 = ig * 128;
        src = qraw; dst = qf + (size_t)bh * (QLEN * NF);
    } else {                         // k: bh(128) x 8 groups of 128 j
        int blk2 = blk - 512;
        int bh = blk2 >> 3, jg = blk2 & 7;
        b = bh >> 4; hh = bh & 15; seq0 = jg * 128;
        src = kraw; dst = kf + (size_t)bh * (KLEN * NF);
    }

    // ---- stage + relu: 4 passes, 16B/thread; 8 rows x full 128B lines/instr
    #pragma unroll
    for (int p = 0; p < 4; ++p) {
        int u   = p * 256 + t;
        int row = u >> 3;
        int c0  = (u & 7) * 8;     // element offset within the 64-col slab
        u32x4 x = *(const u32x4*)(src + ((size_t)(seq0 + row) * 8 + b) * 1024 +
                                  hh * 64 + c0);
        char* gbase = (char*)G + row * 276 + c0 * 2;
        #pragma unroll
        for (int k = 0; k < 4; ++k) {
            unsigned int xk = x[k];
            float x0 = __builtin_bit_cast(float, xk << 16);
            float x1 = __builtin_bit_cast(float, xk & 0xffff0000u);
            float a0 = fmaxf(x0, 0.f), a1 = fmaxf(x1, 0.f);
            float b0 = fmaxf(-x0, 0.f), b1 = fmaxf(-x1, 0.f);
            unsigned int lo, hi;
            asm("v_cvt_pk_bf16_f32 %0, %1, %2" : "=v"(lo) : "v"(a0), "v"(a1));
            asm("v_cvt_pk_bf16_f32 %0, %1, %2" : "=v"(hi) : "v"(b0), "v"(b1));
            *(unsigned int*)(gbase + k * 4)       = lo;   // g[c0..]   = relu(x)
            *(unsigned int*)(gbase + 128 + k * 4) = hi;   // g[64+c0..]= relu(-x)
        }
    }
    __syncthreads();

    // ---- features: wave w -> rows (w>>1)*64 + l, half hs = w&1 (uniform)
    const int w    = t >> 6;
    const int l    = t & 63;
    const int rowc = (w >> 1) * 64 + l;
    const int hs   = w & 1;
    const unsigned short* gr = G + rowc * 138;
    const int seq = seq0 + rowc;
    unsigned short* drow = dst + (size_t)(seq >> 6) * (64 * NF) + (seq & 63) * 8 +
                           hs * (24 * 512);
    if (hs == 0) dpfp_half<0>(gr, drow);
    else         dpfp_half<192>(gr, drow);
}

// ---------------------------------------------------------------------------
// V transpose: v_raw [8192=(j,b)][1024=(h,d)] bf16 -> vt [b,h][d][KLEN] bf16.
// ---------------------------------------------------------------------------
__global__ __launch_bounds__(256)
void vtrans_kernel(const unsigned short* __restrict__ vraw,
                   unsigned short* __restrict__ vt)
{
    __shared__ unsigned short S[256][72];
    const int t  = threadIdx.x;
    const int jc = blockIdx.x, hh = blockIdx.y, b = blockIdx.z;
    const unsigned short* src = vraw + (size_t)((jc * 256 + t) * 8 + b) * 1024 + hh * 64;
    #pragma unroll
    for (int c = 0; c < 8; ++c)
        *(u32x4*)&S[t][c * 8] = *(const u32x4*)(src + c * 8);
    __syncthreads();
    const int d = t >> 2, qq = t & 3;
    unsigned short* dst = vt + ((size_t)(b * NH + hh) * HD + d) * KLEN + jc * 256 + qq * 64;
    #pragma unroll
    for (int c8 = 0; c8 < 8; ++c8) {
        u16x8 o;
        #pragma unroll
        for (int e = 0; e < 8; ++e) o[e] = S[qq * 64 + c8 * 8 + e][d];
        *(u16x8*)(dst + c8 * 8) = o;
    }
}

// ---------------------------------------------------------------------------
// MFMA attention, K/V LDS-staged per j-tile. Panel-grouped XCD swizzle:
// bid = P%8 + 8*it + 64*(P/8); P = b*16+n. qf/kf chunk-blocked:
//   feat[bh][rb][c48][row64][e8]
// ---------------------------------------------------------------------------
__global__ __launch_bounds__(256)
void attn_mfma_kernel(const unsigned short* __restrict__ qf,
                      const unsigned short* __restrict__ kf,
                      const unsigned short* __restrict__ vt,
                      unsigned short* __restrict__ avec)
{
    __shared__ unsigned short Ks[64 * 384];   // rows 768B, chunk^row&7 swizzle
    __shared__ unsigned short Vs[64 * 64];
    __shared__ float Ss[64][68];

    const int t  = threadIdx.x;
    const int w  = t >> 6;
    const int l  = t & 63;
    const int lj = l & 15;
    const int lg = l >> 4;

    const int bid = blockIdx.x;
    const int P   = (bid & 7) + ((bid >> 6) << 3);  // panel 0..127 (b*16+n)
    const int it  = (bid >> 3) & 7;
    const int n   = P & 15;
    const int b   = P >> 4;

    const unsigned short* qpan = qf + (size_t)P * (QLEN * NF) + it * (64 * NF);
    const char* kpan = (const char*)(kf + (size_t)P * (KLEN * NF));
    const unsigned short* vbase = vt + (size_t)(b * NH + n) * HD * KLEN;

    // K staging: LDS 16B-slot S16=(w*12+u)*64+l -> (row, c_lds); source chunk
    // cg = unXOR(c_lds); source 16B index within jt block = cg*64 + row
    int koff[12];
    #pragma unroll
    for (int u = 0; u < 12; ++u) {
        int S16 = (w * 12 + u) * 64 + l;
        int row = S16 / 48;
        int c   = S16 - row * 48;
        int cg  = (c & ~7) | ((c & 7) ^ (row & 7));
        koff[u] = (cg * 64 + row) * 16;
    }
    int voff[2];
    #pragma unroll
    for (int uu = 0; uu < 2; ++uu) {
        int d = (w * 2 + uu) * 8 + (l >> 3);
        int c = (l & 7) ^ (l >> 3);
        voff[uu] = d * (KLEN * 2) + c * 16;
    }

    // Q fragments: 16 lanes read 256B contiguous per frag
    bf16x8 qfr[12];
    #pragma unroll
    for (int ks = 0; ks < 12; ++ks)
        qfr[ks] = *(const bf16x8*)(qpan + (ks * 4 + lg) * 512 + (w * 16 + lj) * 8);

    v4f num[4] = {};
    float den[4] = {0.f, 0.f, 0.f, 0.f};

    const int jt_end = it + 8;
    for (int jt = 0; jt <= jt_end; ++jt) {
        __syncthreads();
        const char* ktile = kpan + (size_t)jt * (64 * NF * 2);
        #pragma unroll
        for (int u = 0; u < 12; ++u)
            gll16(ktile + koff[u], (char*)Ks + (w * 12 + u) * 1024);
        const char* vtile = (const char*)vbase + jt * 128;
        #pragma unroll
        for (int uu = 0; uu < 2; ++uu)
            gll16(vtile + voff[uu], (char*)Vs + (w * 2 + uu) * 1024);
        __syncthreads();

        v4f sacc[4] = {};
        #pragma unroll
        for (int jf = 0; jf < 4; ++jf) {
            const int row = jf * 16 + lj;
            const char* krow = (const char*)Ks + row * 768;
            #pragma unroll
            for (int ks = 0; ks < 12; ++ks) {
                int c   = ks * 4 + lg;
                int swz = (c & ~7) | ((c & 7) ^ (row & 7));
                bf16x8 kfr = *(const bf16x8*)(krow + swz * 16);
                sacc[jf] = __builtin_amdgcn_mfma_f32_16x16x32_bf16(
                               qfr[ks], kfr, sacc[jf], 0, 0, 0);
            }
        }

        const bool diag = (jt == jt_end);
        #pragma unroll
        for (int jf = 0; jf < 4; ++jf) {
            #pragma unroll
            for (int r = 0; r < 4; ++r) {
                float sv = sacc[jf][r];
                int li  = 4 * lg + r;
                int ljj = jf * 16 + lj;
                if (diag && ljj > (w * 16 + li)) sv = 0.f;
                den[r] += sv;
                Ss[w * 16 + li][ljj] = sv;
            }
        }

        #pragma unroll
        for (int kk = 0; kk < 2; ++kk) {
            const float* prow = &Ss[w * 16 + lj][kk * 32 + lg * 8];
            v4f plo = *(const v4f*)prow;
            v4f phi = *(const v4f*)(prow + 4);
            unsigned int w0, w1, w2, w3;
            asm("v_cvt_pk_bf16_f32 %0, %1, %2" : "=v"(w0) : "v"(plo[0]), "v"(plo[1]));
            asm("v_cvt_pk_bf16_f32 %0, %1, %2" : "=v"(w1) : "v"(plo[2]), "v"(plo[3]));
            asm("v_cvt_pk_bf16_f32 %0, %1, %2" : "=v"(w2) : "v"(phi[0]), "v"(phi[1]));
            asm("v_cvt_pk_bf16_f32 %0, %1, %2" : "=v"(w3) : "v"(phi[2]), "v"(phi[3]));
            u32x4 pw = {w0, w1, w2, w3};
            bf16x8 pa = __builtin_bit_cast(bf16x8, pw);
            #pragma unroll
            for (int fd = 0; fd < 4; ++fd) {
                int row = fd * 16 + lj;
                int swz = (kk * 4 + lg) ^ (row & 7);
                bf16x8 vb = *(const bf16x8*)((const char*)Vs + row * 128 + swz * 16);
                num[fd] = __builtin_amdgcn_mfma_f32_16x16x32_bf16(
                              pa, vb, num[fd], 0, 0, 0);
            }
        }
    }

    #pragma unroll
    for (int r = 0; r < 4; ++r) {
        float v = den[r];
        v += __shfl_xor(v, 1, 16);
        v += __shfl_xor(v, 2, 16);
        v += __shfl_xor(v, 4, 16);
        v += __shfl_xor(v, 8, 16);
        den[r] = v;
    }

    #pragma unroll
    for (int r = 0; r < 4; ++r) {
        float minv = ATT_SCALE / (den[r] * ATT_SCALE + EPSV);
        int gi = it * 64 + w * 16 + 4 * lg + r;
        unsigned short* orow = avec + ((size_t)gi * BB + b) * DMODEL + n * HD;
        #pragma unroll
        for (int fd = 0; fd < 4; ++fd)
            orow[fd * 16 + lj] = f2bf(num[fd][r] * minv);
    }
}

// ---------------------------------------------------------------------------
// Row LayerNorm over DM=1024.
// ---------------------------------------------------------------------------
__global__ __launch_bounds__(256)
void ln_kernel(const float* __restrict__ x, const float* __restrict__ gamma,
               const float* __restrict__ beta, float* __restrict__ out)
{
    const int row = blockIdx.x;
    const int t = threadIdx.x;
    const float* xr = x + (size_t)row * DMODEL;
    v4f xv = *(const v4f*)(xr + (t << 2));
    float s1 = xv[0] + xv[1] + xv[2] + xv[3];
    float s2 = xv[0]*xv[0] + xv[1]*xv[1] + xv[2]*xv[2] + xv[3]*xv[3];
    #pragma unroll
    for (int off = 32; off > 0; off >>= 1) {
        s1 += __shfl_down(s1, off);
        s2 += __shfl_down(s2, off);
    }
    __shared__ float red[2][4];
    __shared__ float mv[2];
    const int wave = t >> 6;
    if ((t & 63) == 0) { red[0][wave] = s1; red[1][wave] = s2; }
    __syncthreads();
    if (t == 0) {
        float a = red[0][0] + red[0][1] + red[0][2] + red[0][3];
        float q = red[1][0] + red[1][1] + red[1][2] + red[1][3];
        float mu  = a * (1.f / DMODEL);
        float var = q * (1.f / DMODEL) - mu * mu;
        mv[0] = mu;
        mv[1] = rsqrtf(var + EPSV);
    }
    __syncthreads();
    float mu = mv[0], rs = mv[1];
    v4f gv = *(const v4f*)(gamma + (t << 2));
    v4f bv = *(const v4f*)(beta + (t << 2));
    v4f o;
    #pragma unroll
    for (int e = 0; e < 4; ++e) o[e] = (xv[e] - mu) * rs * gv[e] + bv[e];
    *(v4f*)(out + (size_t)row * DMODEL + (t << 2)) = o;
}

extern "C" void kernel_launch(void* const* d_in, const int* in_sizes, int n_in,
                              void* d_out, int out_size, void* d_ws, size_t ws_size,
                              hipStream_t stream)
{
    const float* h     = (const float*)d_in[0];
    const float* mems  = (const float*)d_in[1];
    const float* Wq    = (const float*)d_in[2];
    const float* Wkv   = (const float*)d_in[3];
    const float* Wo    = (const float*)d_in[4];
    const float* gamma = (const float*)d_in[5];
    const float* beta  = (const float*)d_in[6];
    // d_in[7] = attn_mask: causal structure computed analytically, ignored.

    char* ws = (char*)d_ws;
    unsigned short* qf   = (unsigned short*)(ws);             // [0, 50.33M)
    unsigned short* kf   = (unsigned short*)(ws + 50331648);  // [50.33M, 151.0M)
    unsigned short* kraw = (unsigned short*)(ws + 150994944); // 16.78M
    unsigned short* vt   = kraw;                              // overlay after dpfp
    unsigned short* vraw = (unsigned short*)(ws + 167772160); // 16.78M
    unsigned short* cbf  = (unsigned short*)(ws + 184549376); // 16.78M
    unsigned short* qraw = cbf;                               // overlay mems-half after mm1
    unsigned short* avec = cbf;                               // overlay after dpfp
    float* xws = (float*)(ws);                                // overlay qf after attn

    unsigned short* wqb  = (unsigned short*)d_out;            // bf16 weights in d_out
    unsigned short* wkvb = wqb + 1048576;
    unsigned short* wob  = wkvb + 2097152;

    cvt_all_kernel<<<12288, 256, 0, stream>>>(h, mems, Wq, Wkv, Wo, cbf, wqb, wkvb, wob);
    mm128_kernel<1><<<dim3(64, 16), 256, 0, stream>>>(cbf, wkvb, nullptr, kraw, vraw, nullptr);
    mm128_kernel<0><<<dim3(32, 8), 256, 0, stream>>>(cbf + 4194304, wqb, nullptr, qraw, nullptr, nullptr);
    dpfp_kernel<<<1536, 256, 0, stream>>>(qraw, kraw, qf, kf);
    vtrans_kernel<<<dim3(4, 16, 8), 256, 0, stream>>>(vraw, vt);
    attn_mfma_kernel<<<1024, 256, 0, stream>>>(qf, kf, vt, avec);
    mm128_kernel<2><<<dim3(32, 8), 256, 0, stream>>>(avec, wob, h, nullptr, nullptr, xws);
    ln_kernel<<<4096, 256, 0, stream>>>(xws, gamma, beta, (float*)d_out);
}

// Round 8
// 219.757 us; speedup vs baseline: 2.8680x; 1.2054x over previous
//
#include <hip/hip_runtime.h>

#define QLEN 512
#define MLEN 512
#define KLEN 1024
#define BB   8
#define DMODEL 1024
#define NH   16
#define HD   64
#define NF   384
#define ATT_SCALE 0.125f
#define EPSV 1e-5f

typedef float v4f __attribute__((ext_vector_type(4)));
typedef float f32x16 __attribute__((ext_vector_type(16)));
typedef short bf16x8 __attribute__((ext_vector_type(8)));
typedef unsigned int u32x4 __attribute__((ext_vector_type(4)));
typedef unsigned int u32x2 __attribute__((ext_vector_type(2)));
typedef unsigned short u16x8 __attribute__((ext_vector_type(8)));

__device__ __forceinline__ unsigned short f2bf(float f) {
    unsigned int x = __builtin_bit_cast(unsigned int, f);
    x += 0x7fffu + ((x >> 16) & 1u);
    return (unsigned short)(x >> 16);
}

__device__ __forceinline__ void gll16(const void* g, void* l) {
    __builtin_amdgcn_global_load_lds(
        (const __attribute__((address_space(1))) unsigned int*)g,
        (__attribute__((address_space(3))) unsigned int*)l, 16, 0, 0);
}

// ---------------------------------------------------------------------------
// Fused f32->bf16 converts: mems+h -> cbf (c matrix), weights -> bf16 scratch
// ---------------------------------------------------------------------------
__global__ __launch_bounds__(256)
void cvt_all_kernel(const float* __restrict__ h, const float* __restrict__ mems,
                    const float* __restrict__ Wq, const float* __restrict__ Wkv,
                    const float* __restrict__ Wo,
                    unsigned short* __restrict__ cbf, unsigned short* __restrict__ wqb,
                    unsigned short* __restrict__ wkvb, unsigned short* __restrict__ wob)
{
    int blk = blockIdx.x;
    const float* src; unsigned short* dst; int base;
    if (blk < 4096)       { src = mems; dst = cbf;           base = blk; }
    else if (blk < 8192)  { src = h;    dst = cbf + 4194304; base = blk - 4096; }
    else if (blk < 9216)  { src = Wq;   dst = wqb;           base = blk - 8192; }
    else if (blk < 11264) { src = Wkv;  dst = wkvb;          base = blk - 9216; }
    else                  { src = Wo;   dst = wob;           base = blk - 11264; }
    int i = (base * 256 + threadIdx.x) * 4;
    v4f v = *(const v4f*)(src + i);
    unsigned int p0, p1;
    asm("v_cvt_pk_bf16_f32 %0, %1, %2" : "=v"(p0) : "v"(v[0]), "v"(v[1]));
    asm("v_cvt_pk_bf16_f32 %0, %1, %2" : "=v"(p1) : "v"(v[2]), "v"(v[3]));
    uint2 u; u.x = p0; u.y = p1;
    *(uint2*)(dst + i) = u;
}

// ---------------------------------------------------------------------------
// Pure MFMA GEMM, 128x128 tile, BK=64, 4 waves (each 64x64 = 4x4 frags).
// MODE 0: out = q_raw bf16; MODE 1: outK/outV = k_raw/v_raw bf16;
// MODE 2: xo f32 = C + hres
// ---------------------------------------------------------------------------
template<int MODE>
__global__ __launch_bounds__(256)
void mm128_kernel(const unsigned short* __restrict__ Abf,
                  const unsigned short* __restrict__ Bbf,
                  const float* __restrict__ hres,
                  unsigned short* __restrict__ outK,
                  unsigned short* __restrict__ outV,
                  float* __restrict__ xo)
{
    __shared__ unsigned short As[128 * 64];
    __shared__ unsigned short Bs[128 * 64];

    const int t  = threadIdx.x;
    const int w  = t >> 6;
    const int l  = t & 63;
    const int lj = l & 15;
    const int lg = l >> 4;
    const int m0 = blockIdx.x * 128;
    const int n0 = blockIdx.y * 128;
    const int wr = w >> 1, wc = w & 1;
    const int rsub = l >> 3;
    const int csw  = ((l & 7) ^ rsub) * 16;

    v4f acc[4][4] = {};

    for (int s = 0; s < 16; ++s) {
        const int k0b = s * 128;
        __syncthreads();
        #pragma unroll
        for (int u = 0; u < 4; ++u) {
            int ra = w * 32 + u * 8;
            gll16((const char*)Abf + (size_t)(m0 + ra + rsub) * 2048 + k0b + csw,
                  (char*)As + ra * 128);
            gll16((const char*)Bbf + (size_t)(n0 + ra + rsub) * 2048 + k0b + csw,
                  (char*)Bs + ra * 128);
        }
        __syncthreads();
        #pragma unroll
        for (int ks = 0; ks < 2; ++ks) {
            bf16x8 af[4], bfr[4];
            #pragma unroll
            for (int m = 0; m < 4; ++m) {
                int row = wr * 64 + m * 16 + lj;
                int c = ks * 4 + lg;
                af[m] = *(const bf16x8*)((const char*)As + row * 128 +
                                         ((c ^ (row & 7)) * 16));
            }
            #pragma unroll
            for (int nn = 0; nn < 4; ++nn) {
                int row = wc * 64 + nn * 16 + lj;
                int c = ks * 4 + lg;
                bfr[nn] = *(const bf16x8*)((const char*)Bs + row * 128 +
                                           ((c ^ (row & 7)) * 16));
            }
            #pragma unroll
            for (int m = 0; m < 4; ++m)
                #pragma unroll
                for (int nn = 0; nn < 4; ++nn)
                    acc[m][nn] = __builtin_amdgcn_mfma_f32_16x16x32_bf16(
                                     af[m], bfr[nn], acc[m][nn], 0, 0, 0);
        }
    }

    #pragma unroll
    for (int m = 0; m < 4; ++m) {
        #pragma unroll
        for (int rr = 0; rr < 4; ++rr) {
            int row = m0 + wr * 64 + m * 16 + 4 * lg + rr;
            #pragma unroll
            for (int nn = 0; nn < 4; ++nn) {
                int col = n0 + wc * 64 + nn * 16 + lj;
                float v = acc[m][nn][rr];
                if constexpr (MODE == 2) {
                    xo[(size_t)row * 1024 + col] = v + hres[(size_t)row * 1024 + col];
                } else if constexpr (MODE == 0) {
                    outK[(size_t)row * 1024 + col] = f2bf(v);
                } else {
                    if (n0 < 1024) outK[(size_t)row * 1024 + col] = f2bf(v);
                    else           outV[(size_t)row * 1024 + (col - 1024)] = f2bf(v);
                }
            }
        }
    }
}

// ---------------------------------------------------------------------------
// DPFP feature kernel — LDS-resident g. Output chunk-blocked:
//   feat[bh][rb][c48][row64][e8]
// ---------------------------------------------------------------------------
__device__ __forceinline__ float gld(const unsigned short* gr, int idx) {
    return __builtin_bit_cast(float, ((unsigned int)gr[idx]) << 16);
}

template<int FBASE>
__device__ __forceinline__ void dpfp_half(const unsigned short* __restrict__ gr,
                                          unsigned short* __restrict__ drow)
{
    #pragma unroll
    for (int c = 0; c < 24; ++c) {
        unsigned int w4[4];
        #pragma unroll
        for (int q2 = 0; q2 < 4; ++q2) {
            const int f  = FBASE + c * 8 + q2 * 2;
            const int r0 = (f >> 7) + 1,       t0 = f & 127,       u0 = (t0 - r0) & 127;
            const int f1 = f + 1;
            const int r1 = (f1 >> 7) + 1,      t1 = f1 & 127,      u1 = (t1 - r1) & 127;
            float p0 = gld(gr, t0) * gld(gr, u0);
            float p1 = gld(gr, t1) * gld(gr, u1);
            asm("v_cvt_pk_bf16_f32 %0, %1, %2" : "=v"(w4[q2]) : "v"(p0), "v"(p1));
        }
        u32x4 st = {w4[0], w4[1], w4[2], w4[3]};
        *(u32x4*)(drow + c * 512) = st;
    }
}

__global__ __launch_bounds__(256)
void dpfp_kernel(const unsigned short* __restrict__ qraw,
                 const unsigned short* __restrict__ kraw,
                 unsigned short* __restrict__ qf, unsigned short* __restrict__ kf)
{
    __shared__ unsigned short G[128 * 138];

    const int t   = threadIdx.x;
    const int blk = blockIdx.x;

    const unsigned short* src; unsigned short* dst; int b, hh, seq0;
    if (blk < 512) {
        int bh = blk >> 2, ig = blk & 3;
        b = bh >> 4; hh = bh & 15; seq0 = ig * 128;
        src = qraw; dst = qf + (size_t)bh * (QLEN * NF);
    } else {
        int blk2 = blk - 512;
        int bh = blk2 >> 3, jg = blk2 & 7;
        b = bh >> 4; hh = bh & 15; seq0 = jg * 128;
        src = kraw; dst = kf + (size_t)bh * (KLEN * NF);
    }

    #pragma unroll
    for (int p = 0; p < 4; ++p) {
        int u   = p * 256 + t;
        int row = u >> 3;
        int c0  = (u & 7) * 8;
        u32x4 x = *(const u32x4*)(src + ((size_t)(seq0 + row) * 8 + b) * 1024 +
                                  hh * 64 + c0);
        char* gbase = (char*)G + row * 276 + c0 * 2;
        #pragma unroll
        for (int k = 0; k < 4; ++k) {
            unsigned int xk = x[k];
            float x0 = __builtin_bit_cast(float, xk << 16);
            float x1 = __builtin_bit_cast(float, xk & 0xffff0000u);
            float a0 = fmaxf(x0, 0.f), a1 = fmaxf(x1, 0.f);
            float b0 = fmaxf(-x0, 0.f), b1 = fmaxf(-x1, 0.f);
            unsigned int lo, hig;
            asm("v_cvt_pk_bf16_f32 %0, %1, %2" : "=v"(lo) : "v"(a0), "v"(a1));
            asm("v_cvt_pk_bf16_f32 %0, %1, %2" : "=v"(hig) : "v"(b0), "v"(b1));
            *(unsigned int*)(gbase + k * 4)       = lo;
            *(unsigned int*)(gbase + 128 + k * 4) = hig;
        }
    }
    __syncthreads();

    const int w    = t >> 6;
    const int l    = t & 63;
    const int rowc = (w >> 1) * 64 + l;
    const int hs   = w & 1;
    const unsigned short* gr = G + rowc * 138;
    const int seq = seq0 + rowc;
    unsigned short* drow = dst + (size_t)(seq >> 6) * (64 * NF) + (seq & 63) * 8 +
                           hs * (24 * 512);
    if (hs == 0) dpfp_half<0>(gr, drow);
    else         dpfp_half<192>(gr, drow);
}

// ---------------------------------------------------------------------------
// V transpose: v_raw [8192=(j,b)][1024=(h,d)] bf16 -> vt [b,h][d][KLEN] bf16.
// ---------------------------------------------------------------------------
__global__ __launch_bounds__(256)
void vtrans_kernel(const unsigned short* __restrict__ vraw,
                   unsigned short* __restrict__ vt)
{
    __shared__ unsigned short S[256][72];
    const int t  = threadIdx.x;
    const int jc = blockIdx.x, hh = blockIdx.y, b = blockIdx.z;
    const unsigned short* src = vraw + (size_t)((jc * 256 + t) * 8 + b) * 1024 + hh * 64;
    #pragma unroll
    for (int c = 0; c < 8; ++c)
        *(u32x4*)&S[t][c * 8] = *(const u32x4*)(src + c * 8);
    __syncthreads();
    const int d = t >> 2, qq = t & 3;
    unsigned short* dst = vt + ((size_t)(b * NH + hh) * HD + d) * KLEN + jc * 256 + qq * 64;
    #pragma unroll
    for (int c8 = 0; c8 < 8; ++c8) {
        u16x8 o;
        #pragma unroll
        for (int e = 0; e < 8; ++e) o[e] = S[qq * 64 + c8 * 8 + e][d];
        *(u16x8*)(dst + c8 * 8) = o;
    }
}

// ---------------------------------------------------------------------------
// MFMA attention v2: 32x32 MFMA, swapped QK^T (S^T in regs), in-register P
// via cvt_pk + permlane32_swap (no Ss LDS). Block = 128 i x 64 j-tile,
// 4 waves x 32 i. Grid swizzle: bid = (P&7) + 8*(it + 4*(P>>3)).
// ---------------------------------------------------------------------------
__global__ __launch_bounds__(256, 2)
void attn_mfma_kernel(const unsigned short* __restrict__ qf,
                      const unsigned short* __restrict__ kf,
                      const unsigned short* __restrict__ vt,
                      unsigned short* __restrict__ avec)
{
    __shared__ unsigned short Ks[64 * 384];   // 48KB, rows 768B, chunk^row&7
    __shared__ unsigned short Vs[64 * 64];    // 8KB, rows(d) 128B, chunk^d&7
    __shared__ float Ds[4][32];

    const int t  = threadIdx.x;
    const int w  = t >> 6;
    const int l  = t & 63;
    const int li = l & 31;
    const int hi = l >> 5;

    const int bid = blockIdx.x;
    const int it  = (bid >> 3) & 3;
    const int P   = ((bid >> 5) << 3) + (bid & 7);
    const int n   = P & 15;
    const int b   = P >> 4;

    const unsigned short* qpan = qf + (size_t)P * (QLEN * NF);
    const char* kpan = (const char*)(kf + (size_t)P * (KLEN * NF));
    const unsigned short* vbase = vt + (size_t)P * HD * KLEN;

    int koff[12];
    #pragma unroll
    for (int u = 0; u < 12; ++u) {
        int S16 = (w * 12 + u) * 64 + l;
        int row = S16 / 48;
        int c   = S16 - row * 48;
        int cg  = (c & ~7) | ((c & 7) ^ (row & 7));
        koff[u] = (cg * 64 + row) * 16;
    }
    int voff[2];
    #pragma unroll
    for (int uu = 0; uu < 2; ++uu) {
        int s  = (w * 2 + uu) * 64 + l;
        int d  = s >> 3;
        int cl = s & 7;
        int cg = cl ^ (d & 7);
        voff[uu] = d * (KLEN * 2) + cg * 16;
    }

    // Q fragments (B operand): lane(col=i=li, k=8*hi+e), 24 k-slices
    bf16x8 qfr[24];
    {
        const unsigned short* qb = qpan + (size_t)(it * 2 + (w >> 1)) * (64 * NF)
                                   + ((w & 1) * 32 + li) * 8;
        #pragma unroll
        for (int ks = 0; ks < 24; ++ks)
            qfr[ks] = *(const bf16x8*)(qb + (ks * 2 + hi) * 512);
    }

    f32x16 num[2] = {};
    float den_acc = 0.f;

    const int ig         = it * 128 + w * 32 + li;    // this lane's i (S-col)
    const int my_jt_end  = 2 * it + 8 + (w >> 1);
    const int jt_blk_end = 2 * it + 9;

    for (int jt = 0; jt <= jt_blk_end; ++jt) {
        __syncthreads();
        const char* ktile = kpan + (size_t)jt * (64 * NF * 2);
        #pragma unroll
        for (int u = 0; u < 12; ++u)
            gll16(ktile + koff[u], (char*)Ks + (w * 12 + u) * 1024);
        const char* vtile = (const char*)vbase + jt * 128;
        #pragma unroll
        for (int uu = 0; uu < 2; ++uu)
            gll16(vtile + voff[uu], (char*)Vs + (w * 2 + uu) * 1024);
        __syncthreads();

        if (jt > my_jt_end) continue;

        // ---- S^T = K·Q: sacc[jf] holds S[j = jf*32 + crow(reg,hi)][i = li] ----
        f32x16 sacc0 = {};
        f32x16 sacc1 = {};
        #pragma unroll
        for (int ks = 0; ks < 24; ++ks) {
            int c = ks * 2 + hi;
            {
                int row = li;
                int cs  = (c & ~7) | ((c & 7) ^ (row & 7));
                bf16x8 kfr = *(const bf16x8*)((const char*)Ks + row * 768 + cs * 16);
                sacc0 = __builtin_amdgcn_mfma_f32_32x32x16_bf16(kfr, qfr[ks], sacc0, 0, 0, 0);
            }
            {
                int row = 32 + li;
                int cs  = (c & ~7) | ((c & 7) ^ (row & 7));
                bf16x8 kfr = *(const bf16x8*)((const char*)Ks + row * 768 + cs * 16);
                sacc1 = __builtin_amdgcn_mfma_f32_32x32x16_bf16(kfr, qfr[ks], sacc1, 0, 0, 0);
            }
        }

        // ---- causal mask on the diagonal tile + den accumulate ----
        if (jt == my_jt_end) {
            const int joff = jt * 64 - MLEN + 4 * hi;   // j_global - 512 (reg base)
            #pragma unroll
            for (int reg = 0; reg < 16; ++reg) {
                int jr = (reg & 3) + 8 * (reg >> 2);
                if (joff + jr > ig)      sacc0[reg] = 0.f;
                if (joff + 32 + jr > ig) sacc1[reg] = 0.f;
            }
        }
        {
            float dpart = 0.f;
            #pragma unroll
            for (int reg = 0; reg < 16; ++reg) dpart += sacc0[reg] + sacc1[reg];
            den_acc += dpart + __shfl_xor(dpart, 32);
        }

        // ---- P -> bf16 A-frags (cvt_pk + permlane32_swap), PV MFMA ----
        #pragma unroll
        for (int jf = 0; jf < 2; ++jf) {
            const f32x16 sc = jf ? sacc1 : sacc0;
            unsigned int c01, c23, c45, c67, c89, cab, ccd, cef;
            asm("v_cvt_pk_bf16_f32 %0, %1, %2" : "=v"(c01) : "v"(sc[0]),  "v"(sc[1]));
            asm("v_cvt_pk_bf16_f32 %0, %1, %2" : "=v"(c23) : "v"(sc[2]),  "v"(sc[3]));
            asm("v_cvt_pk_bf16_f32 %0, %1, %2" : "=v"(c45) : "v"(sc[4]),  "v"(sc[5]));
            asm("v_cvt_pk_bf16_f32 %0, %1, %2" : "=v"(c67) : "v"(sc[6]),  "v"(sc[7]));
            asm("v_cvt_pk_bf16_f32 %0, %1, %2" : "=v"(c89) : "v"(sc[8]),  "v"(sc[9]));
            asm("v_cvt_pk_bf16_f32 %0, %1, %2" : "=v"(cab) : "v"(sc[10]), "v"(sc[11]));
            asm("v_cvt_pk_bf16_f32 %0, %1, %2" : "=v"(ccd) : "v"(sc[12]), "v"(sc[13]));
            asm("v_cvt_pk_bf16_f32 %0, %1, %2" : "=v"(cef) : "v"(sc[14]), "v"(sc[15]));
            u32x2 r0 = __builtin_amdgcn_permlane32_swap(c01, c45, false, false);
            u32x2 r1 = __builtin_amdgcn_permlane32_swap(c23, c67, false, false);
            u32x2 r2 = __builtin_amdgcn_permlane32_swap(c89, ccd, false, false);
            u32x2 r3 = __builtin_amdgcn_permlane32_swap(cab, cef, false, false);
            u32x4 pw0 = {r0.x, r1.x, r0.y, r1.y};   // j = jf*32 + kk0*16 + 8hi + e
            u32x4 pw1 = {r2.x, r3.x, r2.y, r3.y};   // kk=1
            bf16x8 pa0 = __builtin_bit_cast(bf16x8, pw0);
            bf16x8 pa1 = __builtin_bit_cast(bf16x8, pw1);
            #pragma unroll
            for (int dd = 0; dd < 2; ++dd) {
                int d = dd * 32 + li;
                {
                    int cs = (jf * 4 + hi) ^ (d & 7);
                    bf16x8 vb = *(const bf16x8*)((const char*)Vs + d * 128 + cs * 16);
                    num[dd] = __builtin_amdgcn_mfma_f32_32x32x16_bf16(pa0, vb, num[dd], 0, 0, 0);
                }
                {
                    int cs = (jf * 4 + 2 + hi) ^ (d & 7);
                    bf16x8 vb = *(const bf16x8*)((const char*)Vs + d * 128 + cs * 16);
                    num[dd] = __builtin_amdgcn_mfma_f32_32x32x16_bf16(pa1, vb, num[dd], 0, 0, 0);
                }
            }
        }
    }

    // ---- den broadcast via tiny per-wave LDS, normalize, store bf16 ----
    if (l < 32) Ds[w][l] = den_acc;
    #pragma unroll
    for (int reg = 0; reg < 16; ++reg) {
        int i_loc = (reg & 3) + 8 * (reg >> 2) + 4 * hi;
        float dv = Ds[w][i_loc];
        float minv = ATT_SCALE / (dv * ATT_SCALE + EPSV);
        int ig2 = it * 128 + w * 32 + i_loc;
        unsigned short* orow = avec + ((size_t)ig2 * BB + b) * DMODEL + n * HD;
        orow[li]      = f2bf(num[0][reg] * minv);
        orow[32 + li] = f2bf(num[1][reg] * minv);
    }
}

// ---------------------------------------------------------------------------
// Row LayerNorm over DM=1024.
// ---------------------------------------------------------------------------
__global__ __launch_bounds__(256)
void ln_kernel(const float* __restrict__ x, const float* __restrict__ gamma,
               const float* __restrict__ beta, float* __restrict__ out)
{
    const int row = blockIdx.x;
    const int t = threadIdx.x;
    const float* xr = x + (size_t)row * DMODEL;
    v4f xv = *(const v4f*)(xr + (t << 2));
    float s1 = xv[0] + xv[1] + xv[2] + xv[3];
    float s2 = xv[0]*xv[0] + xv[1]*xv[1] + xv[2]*xv[2] + xv[3]*xv[3];
    #pragma unroll
    for (int off = 32; off > 0; off >>= 1) {
        s1 += __shfl_down(s1, off);
        s2 += __shfl_down(s2, off);
    }
    __shared__ float red[2][4];
    __shared__ float mv[2];
    const int wave = t >> 6;
    if ((t & 63) == 0) { red[0][wave] = s1; red[1][wave] = s2; }
    __syncthreads();
    if (t == 0) {
        float a = red[0][0] + red[0][1] + red[0][2] + red[0][3];
        float q = red[1][0] + red[1][1] + red[1][2] + red[1][3];
        float mu  = a * (1.f / DMODEL);
        float var = q * (1.f / DMODEL) - mu * mu;
        mv[0] = mu;
        mv[1] = rsqrtf(var + EPSV);
    }
    __syncthreads();
    float mu = mv[0], rs = mv[1];
    v4f gv = *(const v4f*)(gamma + (t << 2));
    v4f bv = *(const v4f*)(beta + (t << 2));
    v4f o;
    #pragma unroll
    for (int e = 0; e < 4; ++e) o[e] = (xv[e] - mu) * rs * gv[e] + bv[e];
    *(v4f*)(out + (size_t)row * DMODEL + (t << 2)) = o;
}

extern "C" void kernel_launch(void* const* d_in, const int* in_sizes, int n_in,
                              void* d_out, int out_size, void* d_ws, size_t ws_size,
                              hipStream_t stream)
{
    const float* h     = (const float*)d_in[0];
    const float* mems  = (const float*)d_in[1];
    const float* Wq    = (const float*)d_in[2];
    const float* Wkv   = (const float*)d_in[3];
    const float* Wo    = (const float*)d_in[4];
    const float* gamma = (const float*)d_in[5];
    const float* beta  = (const float*)d_in[6];
    // d_in[7] = attn_mask: causal structure computed analytically, ignored.

    char* ws = (char*)d_ws;
    unsigned short* qf   = (unsigned short*)(ws);             // [0, 50.33M)
    unsigned short* kf   = (unsigned short*)(ws + 50331648);  // [50.33M, 151.0M)
    unsigned short* kraw = (unsigned short*)(ws + 150994944); // 16.78M
    unsigned short* vt   = kraw;                              // overlay after dpfp
    unsigned short* vraw = (unsigned short*)(ws + 167772160); // 16.78M
    unsigned short* cbf  = (unsigned short*)(ws + 184549376); // 16.78M
    unsigned short* qraw = cbf;                               // overlay mems-half after mm1
    unsigned short* avec = cbf;                               // overlay after dpfp
    float* xws = (float*)(ws);                                // overlay qf after attn

    unsigned short* wqb  = (unsigned short*)d_out;            // bf16 weights in d_out
    unsigned short* wkvb = wqb + 1048576;
    unsigned short* wob  = wkvb + 2097152;

    cvt_all_kernel<<<12288, 256, 0, stream>>>(h, mems, Wq, Wkv, Wo, cbf, wqb, wkvb, wob);
    mm128_kernel<1><<<dim3(64, 16), 256, 0, stream>>>(cbf, wkvb, nullptr, kraw, vraw, nullptr);
    mm128_kernel<0><<<dim3(32, 8), 256, 0, stream>>>(cbf + 4194304, wqb, nullptr, qraw, nullptr, nullptr);
    dpfp_kernel<<<1536, 256, 0, stream>>>(qraw, kraw, qf, kf);
    vtrans_kernel<<<dim3(4, 16, 8), 256, 0, stream>>>(vraw, vt);
    attn_mfma_kernel<<<512, 256, 0, stream>>>(qf, kf, vt, avec);
    mm128_kernel<2><<<dim3(32, 8), 256, 0, stream>>>(avec, wob, h, nullptr, nullptr, xws);
    ln_kernel<<<4096, 256, 0, stream>>>(xws, gamma, beta, (float*)d_out);
}